// Round 1
// 1328.294 us; speedup vs baseline: 1.0776x; 1.0776x over previous
//
#include <hip/hip_runtime.h>
#include <math.h>

#define N_NODES 50000
#define E_EDGES 800000
#define HC 128
#define ED 32
#define WTS 34   // padded LDS stride for transposed We (even -> 8B-aligned float2 reads)

typedef __attribute__((ext_vector_type(8))) short bf16x8;
typedef __attribute__((ext_vector_type(4))) float f32x4;
typedef unsigned short ushort_t;

__device__ __forceinline__ ushort_t f2bf(float f){
    unsigned u = __float_as_uint(f);
    return (ushort_t)((u + 0x7FFFu + ((u >> 16) & 1u)) >> 16);   // RNE
}
__device__ __forceinline__ float bflo(unsigned u){ return __uint_as_float(u << 16); }
__device__ __forceinline__ float bfhi(unsigned u){ return __uint_as_float(u & 0xffff0000u); }

// ============================ CSR build ============================

__global__ void zero_int_kernel(int* __restrict__ p, int n){
    int i = blockIdx.x * blockDim.x + threadIdx.x;
    if (i < n) p[i] = 0;
}

__global__ void hist_kernel(const int* __restrict__ dst, int* __restrict__ cnt, int n_edges){
    int e = blockIdx.x * blockDim.x + threadIdx.x;
    if (e < n_edges) atomicAdd(&cnt[dst[e]], 1);
}

__global__ void scan_kernel(const int* __restrict__ cnt, int* __restrict__ rowptr,
                            int* __restrict__ cursor){
    __shared__ int part[1024];
    const int t = threadIdx.x;
    const int CH = (N_NODES + 1023) / 1024;
    const int base = t * CH;
    int s = 0;
    for (int i = 0; i < CH; i++){
        int idx = base + i;
        if (idx < N_NODES) s += cnt[idx];
    }
    part[t] = s;
    __syncthreads();
    for (int off = 1; off < 1024; off <<= 1){
        int v = (t >= off) ? part[t - off] : 0;
        __syncthreads();
        part[t] += v;
        __syncthreads();
    }
    int off = (t == 0) ? 0 : part[t - 1];
    for (int i = 0; i < CH; i++){
        int idx = base + i;
        if (idx < N_NODES){
            int c = cnt[idx];
            rowptr[idx] = off;
            cursor[idx] = off;
            off += c;
        }
    }
    if (t == 1023) rowptr[N_NODES] = part[1023];
}

__global__ void scatter_kernel(const int* __restrict__ src, const int* __restrict__ dst,
                               int* __restrict__ cursor, int2* __restrict__ es, int n_edges){
    int e = blockIdx.x * blockDim.x + threadIdx.x;
    if (e < n_edges){
        int d = dst[e];
        int pos = atomicAdd(&cursor[d], 1);
        es[pos] = make_int2(e, src[e]);
    }
}

__global__ void permute_attr_kernel(const float* __restrict__ attr, const int2* __restrict__ es,
                                    ushort_t* __restrict__ attr_bf, int n_edges){
    int gid = blockIdx.x * blockDim.x + threadIdx.x;
    int grp = gid >> 5, lane = gid & 31;
    if (grp < n_edges){
        int e = es[grp].x;
        attr_bf[(size_t)grp * ED + lane] = f2bf(attr[(size_t)e * ED + lane]);
    }
}

// ===================== bf16 conversion / weight packing =====================

__global__ void convert_bf16_kernel(const float* __restrict__ X, ushort_t* __restrict__ Y,
                                    int n4){   // n4 = n_elements/4
    int i = blockIdx.x * blockDim.x + threadIdx.x;
    if (i < n4){
        float4 v = ((const float4*)X)[i];
        ushort_t r0 = f2bf(v.x), r1 = f2bf(v.y), r2 = f2bf(v.z), r3 = f2bf(v.w);
        ((ushort4*)Y)[i] = make_ushort4(r0, r1, r2, r3);
    }
}

// pack Wq|Wk|Wv|Ws [K,128] fp32 into fragment-ordered bf16:
// Bpack[((k>>3)*512 + n)*8 + (k&7)] = W_{n>>7}[k*128 + (n&127)]
__global__ void pack_w_kernel(const float* __restrict__ Wq, const float* __restrict__ Wk,
                              const float* __restrict__ Wv, const float* __restrict__ Ws,
                              ushort_t* __restrict__ Bpack, int K){
    int t = blockIdx.x * blockDim.x + threadIdx.x;
    if (t >= K * 512) return;
    int n = t & 511, k = t >> 9;
    const float* W = (n < 128) ? Wq : (n < 256) ? Wk : (n < 384) ? Wv : Ws;
    float val = W[k * HC + (n & 127)];
    Bpack[(((size_t)(k >> 3)) * 512 + n) * 8 + (k & 7)] = f2bf(val);
}

// ===================== MFMA GEMM: [M,K]bf16 @ [K,512]bf16 + bias ====
// block = 4 waves; wave w computes output matrix w (q,k,v,s).
// q,s stored f32; k,v stored bf16 (consumed only by the gather-heavy attn kernel).
template<int K>
__global__ __launch_bounds__(256) void gemm_mfma(
    const ushort_t* __restrict__ Xbf, const ushort_t* __restrict__ Bpack,
    const float* __restrict__ bq, const float* __restrict__ bk,
    const float* __restrict__ bv, const float* __restrict__ bs,
    float* __restrict__ Yq, ushort_t* __restrict__ Ykbf,
    ushort_t* __restrict__ Yvbf, float* __restrict__ Ys, int M)
{
    const int w = threadIdx.x >> 6;
    const int lane = threadIdx.x & 63;
    const int q = lane >> 4, nn = lane & 15;
    const int row0 = blockIdx.x * 32;

    f32x4 acc[2][8];
    #pragma unroll
    for (int mt = 0; mt < 2; mt++)
        #pragma unroll
        for (int nt = 0; nt < 8; nt++)
            acc[mt][nt] = (f32x4){0.f, 0.f, 0.f, 0.f};

    const int r0 = row0 + nn;
    const int r1 = row0 + 16 + nn;
    const bf16x8 zf = (bf16x8){0,0,0,0,0,0,0,0};

    #pragma unroll
    for (int kc = 0; kc < K / 32; kc++){
        bf16x8 a0 = (r0 < M) ? *(const bf16x8*)&Xbf[(size_t)r0 * K + kc * 32 + q * 8] : zf;
        bf16x8 a1 = (r1 < M) ? *(const bf16x8*)&Xbf[(size_t)r1 * K + kc * 32 + q * 8] : zf;
        bf16x8 b[8];
        #pragma unroll
        for (int nt = 0; nt < 8; nt++){
            int n = w * 128 + nt * 16 + nn;
            b[nt] = *(const bf16x8*)&Bpack[(((size_t)(kc * 4 + q)) * 512 + n) * 8];
        }
        #pragma unroll
        for (int nt = 0; nt < 8; nt++){
            acc[0][nt] = __builtin_amdgcn_mfma_f32_16x16x32_bf16(a0, b[nt], acc[0][nt], 0, 0, 0);
            acc[1][nt] = __builtin_amdgcn_mfma_f32_16x16x32_bf16(a1, b[nt], acc[1][nt], 0, 0, 0);
        }
    }

    if (w == 0 || w == 3){
        float* Y = (w == 0) ? Yq : Ys;
        const float* bias = (w == 0) ? bq : bs;
        #pragma unroll
        for (int nt = 0; nt < 8; nt++){
            int col = nt * 16 + nn;
            float bval = bias[col];
            #pragma unroll
            for (int mt = 0; mt < 2; mt++){
                #pragma unroll
                for (int r = 0; r < 4; r++){
                    int row = row0 + mt * 16 + q * 4 + r;
                    if (row < M) Y[(size_t)row * HC + col] = acc[mt][nt][r] + bval;
                }
            }
        }
    } else {
        ushort_t* Yb = (w == 1) ? Ykbf : Yvbf;
        const float* bias = (w == 1) ? bk : bv;
        #pragma unroll
        for (int nt = 0; nt < 8; nt++){
            int col = nt * 16 + nn;
            float bval = bias[col];
            #pragma unroll
            for (int mt = 0; mt < 2; mt++){
                #pragma unroll
                for (int r = 0; r < 4; r++){
                    int row = row0 + mt * 16 + q * 4 + r;
                    if (row < M) Yb[(size_t)row * HC + col] = f2bf(acc[mt][nt][r] + bval);
                }
            }
        }
    }
}

// ===================== fused per-node attention =====================
// 1 wave = 1 node. Lane = h*16+i owns channels (h*32+2i, h*32+2i+1) and attr dims (2i, 2i+1).
// Per-edge reduce: 4-level 16-lane butterfly (all 4 heads at once).
// Edge loop: 4-edge batches, one grouped online-softmax rescale per batch.
// k, v, attr consumed as bf16 (halved gather traffic). norm_a fused into the epilogue.
__global__ __launch_bounds__(256) void fused_attn_kernel(
    const float* __restrict__ qv, const ushort_t* __restrict__ kb,
    const ushort_t* __restrict__ vb, const float* __restrict__ skip,
    const float* __restrict__ attr, const ushort_t* __restrict__ attr_bf, int perm_mode,
    const float* __restrict__ We,
    const int* __restrict__ rowptr, const int2* __restrict__ es,
    float* __restrict__ acsr, float* __restrict__ a_out,
    const float* __restrict__ g, const float* __restrict__ be,
    float* __restrict__ out_f32, ushort_t* __restrict__ out_bf, int apply_ln)
{
    __shared__ float WeT[HC * WTS];       // WeT[c*WTS+d] = We[d*128+c]
    __shared__ float SL[4 * 4 * WTS];     // [wave][head][34] S scratch
    const int t = threadIdx.x;
    for (int idx = t; idx < ED * HC; idx += 256){
        int d = idx >> 7, c = idx & 127;
        WeT[c * WTS + d] = We[idx];
    }
    __syncthreads();

    const int lane = t & 63, wvi = t >> 6;
    const int n = blockIdx.x * 4 + wvi;
    if (n >= N_NODES) return;
    const int h = lane >> 4, li = lane & 15;
    const int ch = h * 32 + 2 * li;              // even global channel

    const float2 q2  = *(const float2*)&qv[(size_t)n * HC + ch];
    const float2 sk2 = *(const float2*)&skip[(size_t)n * HC + ch];

    // QW = We_h^T q_h per (head h, dims 2li, 2li+1)
    float QW0 = 0.f, QW1 = 0.f;
    #pragma unroll
    for (int c2 = 0; c2 < 16; c2++){
        float qa = __shfl(q2.x, (lane & 48) + c2);
        float qb = __shfl(q2.y, (lane & 48) + c2);
        const float2 wa = *(const float2*)&WeT[(h * 32 + 2 * c2) * WTS + 2 * li];
        const float2 wb = *(const float2*)&WeT[(h * 32 + 2 * c2 + 1) * WTS + 2 * li];
        QW0 = fmaf(qa, wa.x, fmaf(qb, wb.x, QW0));
        QW1 = fmaf(qa, wa.y, fmaf(qb, wb.y, QW1));
    }

    const int beg = rowptr[n], end = rowptr[n + 1];
    float m = -1e30f, s = 0.f, accx = 0.f, accy = 0.f, Sx = 0.f, Sy = 0.f;

    for (int i = beg; i < end; i += 4){
        const int cnt = end - i;                       // wave-uniform
        unsigned ku[4], vu[4];
        float af0[4], af1[4];
        #pragma unroll
        for (int j = 0; j < 4; j++){
            ku[j] = 0u; vu[j] = 0u; af0[j] = 0.f; af1[j] = 0.f;
            if (j < cnt){
                const int2 e = es[i + j];
                ku[j] = *(const unsigned*)&kb[(size_t)e.y * HC + ch];
                vu[j] = *(const unsigned*)&vb[(size_t)e.y * HC + ch];
                if (perm_mode){
                    unsigned au = *(const unsigned*)&attr_bf[(size_t)(i + j) * ED + 2 * li];
                    af0[j] = bflo(au); af1[j] = bfhi(au);
                } else {
                    const float* ap = &attr[(size_t)e.x * ED + 2 * li];
                    af0[j] = ap[0]; af1[j] = ap[1];
                }
            }
        }
        float alpha[4];
        #pragma unroll
        for (int j = 0; j < 4; j++){
            float p = fmaf(bflo(ku[j]), q2.x,
                     fmaf(bfhi(ku[j]), q2.y,
                     fmaf(af0[j], QW0, af1[j] * QW1)));
            p += __shfl_xor(p, 1);
            p += __shfl_xor(p, 2);
            p += __shfl_xor(p, 4);
            p += __shfl_xor(p, 8);
            alpha[j] = (j < cnt) ? p * 0.17677669529663687f : -1e38f;
        }
        #pragma unroll
        for (int j = 0; j < 4; j++)
            if (li == 0 && j < cnt) acsr[(size_t)(i + j) * 4 + h] = alpha[j];

        float mn = fmaxf(fmaxf(m, fmaxf(alpha[0], alpha[1])), fmaxf(alpha[2], alpha[3]));
        float sc = __expf(m - mn);
        m = mn;
        float w0 = __expf(alpha[0] - mn), w1 = __expf(alpha[1] - mn);
        float w2 = __expf(alpha[2] - mn), w3 = __expf(alpha[3] - mn);
        s    = fmaf(s,    sc, (w0 + w1) + (w2 + w3));
        accx = fmaf(accx, sc, fmaf(w0, bflo(vu[0]), fmaf(w1, bflo(vu[1]), fmaf(w2, bflo(vu[2]), w3 * bflo(vu[3])))));
        accy = fmaf(accy, sc, fmaf(w0, bfhi(vu[0]), fmaf(w1, bfhi(vu[1]), fmaf(w2, bfhi(vu[2]), w3 * bfhi(vu[3])))));
        Sx   = fmaf(Sx,   sc, fmaf(w0, af0[0], fmaf(w1, af0[1], fmaf(w2, af0[2], w3 * af0[3]))));
        Sy   = fmaf(Sy,   sc, fmaf(w0, af1[0], fmaf(w1, af1[1], fmaf(w2, af1[2], w3 * af1[3]))));
    }

    // ---- E = We_h^T S_h via per-wave LDS transpose ----
    float* SLw = &SL[(wvi * 4 + h) * WTS];
    *(float2*)&SLw[2 * li] = make_float2(Sx, Sy);
    asm volatile("" ::: "memory");     // keep ds_write before ds_read (in-wave LDS is in-order)
    float E0 = 0.f, E1 = 0.f;
    #pragma unroll
    for (int d2 = 0; d2 < 16; d2++){
        const float2 sd = *(const float2*)&SLw[2 * d2];
        const float2 wr0 = *(const float2*)&WeT[ch * WTS + 2 * d2];
        const float2 wr1 = *(const float2*)&WeT[(ch + 1) * WTS + 2 * d2];
        E0 = fmaf(sd.x, wr0.x, fmaf(sd.y, wr0.y, E0));
        E1 = fmaf(sd.x, wr1.x, fmaf(sd.y, wr1.y, E1));
    }

    const float inv = 1.f / (s + 1e-16f);
    float o0 = (accx + E0) * inv + sk2.x;
    float o1 = (accy + E1) * inv + sk2.y;

    if (apply_ln){
        float s1 = o0 + o1, s2 = fmaf(o0, o0, o1 * o1);
        #pragma unroll
        for (int off = 32; off; off >>= 1){
            s1 += __shfl_xor(s1, off);
            s2 += __shfl_xor(s2, off);
        }
        float mu  = s1 * (1.f / 128.f);
        float var = s2 * (1.f / 128.f) - mu * mu;
        float ivs = rsqrtf(var + 1e-5f);
        const float2 gg = *(const float2*)&g[ch];
        const float2 bb = *(const float2*)&be[ch];
        o0 = fmaxf((o0 - mu) * ivs * gg.x + bb.x, 0.f);
        o1 = fmaxf((o1 - mu) * ivs * gg.y + bb.y, 0.f);
        ushort2 st; st.x = f2bf(o0); st.y = f2bf(o1);
        *(ushort2*)&out_bf[(size_t)n * HC + ch] = st;
    } else {
        *(float2*)&out_f32[(size_t)n * HC + ch] = make_float2(o0, o1);
    }

    // ---- fused norm_a: a = exp(raw - m) / (den + 1e-16), scattered to original edge order ----
    asm volatile("s_waitcnt vmcnt(0)" ::: "memory");   // our acsr stores are visible (same wave/L2)
    const float mh = __shfl(m, (lane & 3) << 4);
    const float ih = 1.f / (__shfl(s, (lane & 3) << 4) + 1e-16f);
    for (int f = beg * 4 + lane; f < end * 4; f += 64){
        const int e = es[f >> 2].x;
        a_out[(size_t)e * 4 + (f & 3)] = __expf(acsr[f] - mh) * ih;
    }
}

// ============================ launch ============================

extern "C" void kernel_launch(void* const* d_in, const int* in_sizes, int n_in,
                              void* d_out, int out_size, void* d_ws, size_t ws_size,
                              hipStream_t stream) {
    const float* x    = (const float*)d_in[0];
    const int*   ei   = (const int*)  d_in[1];
    const float* attr = (const float*)d_in[2];
    const float* gln[2]  = { (const float*)d_in[30], (const float*)d_in[32] };
    const float* beln[2] = { (const float*)d_in[31], (const float*)d_in[33] };

    float* out   = (float*)d_out;
    float* h_out = out;
    float* a_out[3] = { out + (size_t)N_NODES * HC,
                        out + (size_t)N_NODES * HC + (size_t)E_EDGES * 4,
                        out + (size_t)N_NODES * HC + (size_t)2 * E_EDGES * 4 };

    // ---- workspace layout (64B-aligned chunks) ----
    char* base = (char*)d_ws;
    size_t off = 0;
    auto alloc = [&](size_t bytes) -> void* {
        void* p = base + off;
        off = (off + bytes + 63) & ~(size_t)63;
        return p;
    };
    const size_t NB = (size_t)N_NODES * HC;
    float* qbuf     = (float*)alloc(NB * 4);
    ushort_t* kbf   = (ushort_t*)alloc(NB * 2);
    ushort_t* vbf   = (ushort_t*)alloc(NB * 2);
    float* sbuf     = (float*)alloc(NB * 4);
    int* rowptr     = (int*)alloc((N_NODES + 1) * 4);
    int* cnt        = (int*)alloc(N_NODES * 4);
    int* cursor     = (int*)alloc(N_NODES * 4);
    int2* es        = (int2*)alloc((size_t)E_EDGES * 8);
    ushort_t* Xbf   = (ushort_t*)alloc((size_t)N_NODES * 256 * 2);
    ushort_t* Hbf   = (ushort_t*)alloc(NB * 2);
    ushort_t* Bpack = (ushort_t*)alloc((size_t)256 * 512 * 2);
    float* acsr     = (float*)alloc((size_t)E_EDGES * 4 * 4);
    ushort_t* attr_bf = (ushort_t*)alloc((size_t)E_EDGES * ED * 2);
    const int perm_mode = (ws_size >= off) ? 1 : 0;

    const int* srcp = ei;
    const int* dstp = ei + E_EDGES;

    // ---- CSR build + conversions (once per launch) ----
    zero_int_kernel<<<(N_NODES + 255) / 256, 256, 0, stream>>>(cnt, N_NODES);
    hist_kernel<<<(E_EDGES + 255) / 256, 256, 0, stream>>>(dstp, cnt, E_EDGES);
    scan_kernel<<<1, 1024, 0, stream>>>(cnt, rowptr, cursor);
    scatter_kernel<<<(E_EDGES + 255) / 256, 256, 0, stream>>>(srcp, dstp, cursor, es, E_EDGES);
    if (perm_mode)
        permute_attr_kernel<<<(E_EDGES * 32 + 255) / 256, 256, 0, stream>>>(attr, es, attr_bf, E_EDGES);
    convert_bf16_kernel<<<((N_NODES * 256 / 4) + 255) / 256, 256, 0, stream>>>(x, Xbf, N_NODES * 256 / 4);

    const int gemm_grid = (N_NODES + 31) / 32;

    for (int l = 0; l < 3; l++){
        const float* Wq = (const float*)d_in[3 + 9 * l + 0];
        const float* bq = (const float*)d_in[3 + 9 * l + 1];
        const float* Wk = (const float*)d_in[3 + 9 * l + 2];
        const float* bk = (const float*)d_in[3 + 9 * l + 3];
        const float* Wv = (const float*)d_in[3 + 9 * l + 4];
        const float* bv = (const float*)d_in[3 + 9 * l + 5];
        const float* We = (const float*)d_in[3 + 9 * l + 6];
        const float* Ws = (const float*)d_in[3 + 9 * l + 7];
        const float* bs = (const float*)d_in[3 + 9 * l + 8];
        const int K = (l == 0) ? 256 : 128;

        pack_w_kernel<<<(K * 512 + 255) / 256, 256, 0, stream>>>(Wq, Wk, Wv, Ws, Bpack, K);
        if (l == 0)
            gemm_mfma<256><<<gemm_grid, 256, 0, stream>>>(Xbf, Bpack, bq, bk, bv, bs,
                                                          qbuf, kbf, vbf, sbuf, N_NODES);
        else
            gemm_mfma<128><<<gemm_grid, 256, 0, stream>>>(Hbf, Bpack, bq, bk, bv, bs,
                                                          qbuf, kbf, vbf, sbuf, N_NODES);

        const float* gg = (l < 2) ? gln[l] : nullptr;
        const float* bb = (l < 2) ? beln[l] : nullptr;
        fused_attn_kernel<<<(N_NODES + 3) / 4, 256, 0, stream>>>(
            qbuf, kbf, vbf, sbuf, attr, attr_bf, perm_mode, We, rowptr, es,
            acsr, a_out[l], gg, bb,
            (l < 2) ? nullptr : h_out, (l < 2) ? Hbf : nullptr, (l < 2) ? 1 : 0);
    }
}

// Round 4
// 1281.080 us; speedup vs baseline: 1.1173x; 1.0369x over previous
//
#include <hip/hip_runtime.h>
#include <math.h>

#define N_NODES 50000
#define E_EDGES 800000
#define HC 128
#define ED 32

typedef __attribute__((ext_vector_type(8))) short bf16x8;
typedef __attribute__((ext_vector_type(4))) float f32x4;
typedef unsigned short ushort_t;

__device__ __forceinline__ ushort_t f2bf(float f){
    unsigned u = __float_as_uint(f);
    return (ushort_t)((u + 0x7FFFu + ((u >> 16) & 1u)) >> 16);   // RNE
}
__device__ __forceinline__ float bflo(unsigned u){ return __uint_as_float(u << 16); }
__device__ __forceinline__ float bfhi(unsigned u){ return __uint_as_float(u & 0xffff0000u); }

// WeT layout: stride 40, per-row quad-rotation. BIJECTIVE (each c owns [c*40, c*40+32)),
// float4-aligned, and read bank-quad = (2r + d4 + 4h + j) mod 8 -> 2-way max (free).
// (Old c*36+skew layout collided c=63 with c=64 -- R2/R3 correctness bug.)
__device__ __forceinline__ int weidx(int c, int d){
    return c * 40 + (((((d >> 2) + ((c >> 3) & 7)) & 7)) << 2) + (d & 3);
}

// ============================ CSR build ============================

__global__ void zero_int_kernel(int* __restrict__ p, int n){
    int i = blockIdx.x * blockDim.x + threadIdx.x;
    if (i < n) p[i] = 0;
}

__global__ void hist_kernel(const int* __restrict__ dst, int* __restrict__ cnt, int n_edges){
    int e = blockIdx.x * blockDim.x + threadIdx.x;
    if (e < n_edges) atomicAdd(&cnt[dst[e]], 1);
}

__global__ void scan_kernel(const int* __restrict__ cnt, int* __restrict__ rowptr,
                            int* __restrict__ cursor){
    __shared__ int part[1024];
    const int t = threadIdx.x;
    const int CH = (N_NODES + 1023) / 1024;
    const int base = t * CH;
    int s = 0;
    for (int i = 0; i < CH; i++){
        int idx = base + i;
        if (idx < N_NODES) s += cnt[idx];
    }
    part[t] = s;
    __syncthreads();
    for (int off = 1; off < 1024; off <<= 1){
        int v = (t >= off) ? part[t - off] : 0;
        __syncthreads();
        part[t] += v;
        __syncthreads();
    }
    int off = (t == 0) ? 0 : part[t - 1];
    for (int i = 0; i < CH; i++){
        int idx = base + i;
        if (idx < N_NODES){
            int c = cnt[idx];
            rowptr[idx] = off;
            cursor[idx] = off;
            off += c;
        }
    }
    if (t == 1023) rowptr[N_NODES] = part[1023];
}

__global__ void scatter_kernel(const int* __restrict__ src, const int* __restrict__ dst,
                               int* __restrict__ cursor, int2* __restrict__ es, int n_edges){
    int e = blockIdx.x * blockDim.x + threadIdx.x;
    if (e < n_edges){
        int d = dst[e];
        int pos = atomicAdd(&cursor[d], 1);
        es[pos] = make_int2(e, src[e]);
    }
}

__global__ void permute_attr_kernel(const float* __restrict__ attr, const int2* __restrict__ es,
                                    ushort_t* __restrict__ attr_bf, int n_edges){
    int gid = blockIdx.x * blockDim.x + threadIdx.x;      // 16 threads / edge, 2 elems each
    int grp = gid >> 4, lane = gid & 15;
    if (grp < n_edges){
        int e = es[grp].x;
        const float2 v = *(const float2*)&attr[(size_t)e * ED + lane * 2];
        unsigned r = (unsigned)f2bf(v.x) | ((unsigned)f2bf(v.y) << 16);
        ((unsigned*)attr_bf)[(size_t)grp * (ED / 2) + lane] = r;
    }
}

// ---------------- degree sort (balance quarters within a wave) ----------------

__global__ void dhist_kernel(const int* __restrict__ rowptr, int* __restrict__ bcnt){
    int n = blockIdx.x * blockDim.x + threadIdx.x;
    if (n < N_NODES){
        int d = rowptr[n + 1] - rowptr[n];
        if (d > 63) d = 63;
        atomicAdd(&bcnt[d], 1);
    }
}

__global__ void dscan_kernel(const int* __restrict__ bcnt, int* __restrict__ bcur){
    __shared__ int sh[64];
    int t = threadIdx.x;
    sh[t] = bcnt[t];
    __syncthreads();
    if (t == 0){
        int acc = 0;
        for (int d = 0; d < 64; d++){ int c = sh[d]; sh[d] = acc; acc += c; }
    }
    __syncthreads();
    bcur[t] = sh[t];
}

__global__ void dscatter_kernel(const int* __restrict__ rowptr, int* __restrict__ bcur,
                                int* __restrict__ norder){
    int n = blockIdx.x * blockDim.x + threadIdx.x;
    if (n < N_NODES){
        int d = rowptr[n + 1] - rowptr[n];
        if (d > 63) d = 63;
        int pos = atomicAdd(&bcur[d], 1);
        norder[pos] = n;
    }
}

// ===================== bf16 conversion / weight packing =====================

__global__ void convert_bf16_kernel(const float* __restrict__ X, ushort_t* __restrict__ Y,
                                    int n4){
    int i = blockIdx.x * blockDim.x + threadIdx.x;
    if (i < n4){
        float4 v = ((const float4*)X)[i];
        ushort_t r0 = f2bf(v.x), r1 = f2bf(v.y), r2 = f2bf(v.z), r3 = f2bf(v.w);
        ((ushort4*)Y)[i] = make_ushort4(r0, r1, r2, r3);
    }
}

// Wqe[k, h*32+d] = sum_c Wq[k, h*32+c] * We[d, h*32+c]; qwb = same from bq.
__global__ void wqe_kernel(const float* __restrict__ Wq, const float* __restrict__ bq,
                           const float* __restrict__ We, float* __restrict__ Wqe,
                           float* __restrict__ qwb, int K){
    int t = blockIdx.x * blockDim.x + threadIdx.x;
    if (t < HC){
        int h5 = (t >> 5) * 32, d = t & 31;
        float acc = 0.f;
        for (int c = 0; c < 32; c++)
            acc += bq[h5 + c] * We[d * HC + h5 + c];
        qwb[t] = acc;
    }
    if (t >= K * HC) return;
    int k = t >> 7, col = t & 127;
    int h5 = (col >> 5) * 32, d = col & 31;
    float acc = 0.f;
    for (int c = 0; c < 32; c++)
        acc += Wq[k * HC + h5 + c] * We[d * HC + h5 + c];
    Wqe[t] = acc;
}

// pack Wq|Wk|Wv|Ws|Wqe [K,128] fp32 into fragment-ordered bf16 (Npack=640):
// Bpack[((k>>3)*640 + n)*8 + (k&7)] = W_{n>>7}[k*128 + (n&127)]
__global__ void pack_w_kernel(const float* __restrict__ Wq, const float* __restrict__ Wk,
                              const float* __restrict__ Wv, const float* __restrict__ Ws,
                              const float* __restrict__ Wqe,
                              ushort_t* __restrict__ Bpack, int K){
    int t = blockIdx.x * blockDim.x + threadIdx.x;
    if (t >= K * 640) return;
    int n = t % 640, k = t / 640;
    const float* W = (n < 128) ? Wq : (n < 256) ? Wk : (n < 384) ? Wv : (n < 512) ? Ws : Wqe;
    float val = W[k * HC + (n & 127)];
    Bpack[(((size_t)(k >> 3)) * 640 + n) * 8 + (k & 7)] = f2bf(val);
}

// ===================== MFMA GEMM: [M,K]bf16 @ [K,640]bf16 + bias ====
// 5 waves; w: 0=q(f32,*scale) 1=k(bf16) 2=v(bf16) 3=skip(f32) 4=QW(f32,*scale)
template<int K>
__global__ __launch_bounds__(320) void gemm_mfma(
    const ushort_t* __restrict__ Xbf, const ushort_t* __restrict__ Bpack,
    const float* __restrict__ b0, const float* __restrict__ b1,
    const float* __restrict__ b2, const float* __restrict__ b3,
    const float* __restrict__ b4,
    float* __restrict__ Yq, ushort_t* __restrict__ Ykbf,
    ushort_t* __restrict__ Yvbf, float* __restrict__ Ys,
    float* __restrict__ Yw, int M)
{
    const int w = threadIdx.x >> 6;
    const int lane = threadIdx.x & 63;
    const int q = lane >> 4, nn = lane & 15;
    const int row0 = blockIdx.x * 32;

    f32x4 acc[2][8];
    #pragma unroll
    for (int mt = 0; mt < 2; mt++)
        #pragma unroll
        for (int nt = 0; nt < 8; nt++)
            acc[mt][nt] = (f32x4){0.f, 0.f, 0.f, 0.f};

    const int r0 = row0 + nn;
    const int r1 = row0 + 16 + nn;
    const bf16x8 zf = (bf16x8){0,0,0,0,0,0,0,0};

    #pragma unroll
    for (int kc = 0; kc < K / 32; kc++){
        bf16x8 a0 = (r0 < M) ? *(const bf16x8*)&Xbf[(size_t)r0 * K + kc * 32 + q * 8] : zf;
        bf16x8 a1 = (r1 < M) ? *(const bf16x8*)&Xbf[(size_t)r1 * K + kc * 32 + q * 8] : zf;
        bf16x8 b[8];
        #pragma unroll
        for (int nt = 0; nt < 8; nt++){
            int n = w * 128 + nt * 16 + nn;
            b[nt] = *(const bf16x8*)&Bpack[(((size_t)(kc * 4 + q)) * 640 + n) * 8];
        }
        #pragma unroll
        for (int nt = 0; nt < 8; nt++){
            acc[0][nt] = __builtin_amdgcn_mfma_f32_16x16x32_bf16(a0, b[nt], acc[0][nt], 0, 0, 0);
            acc[1][nt] = __builtin_amdgcn_mfma_f32_16x16x32_bf16(a1, b[nt], acc[1][nt], 0, 0, 0);
        }
    }

    const float scale = (w == 0 || w == 4) ? 0.17677669529663687f : 1.f;
    const float* bias = (w == 0) ? b0 : (w == 1) ? b1 : (w == 2) ? b2 : (w == 3) ? b3 : b4;

    if (w == 1 || w == 2){
        ushort_t* Yb = (w == 1) ? Ykbf : Yvbf;
        #pragma unroll
        for (int nt = 0; nt < 8; nt++){
            int col = nt * 16 + nn;
            float bval = bias[col];
            #pragma unroll
            for (int mt = 0; mt < 2; mt++){
                #pragma unroll
                for (int r = 0; r < 4; r++){
                    int row = row0 + mt * 16 + q * 4 + r;
                    if (row < M) Yb[(size_t)row * HC + col] = f2bf(acc[mt][nt][r] + bval);
                }
            }
        }
    } else {
        float* Y = (w == 0) ? Yq : (w == 3) ? Ys : Yw;
        #pragma unroll
        for (int nt = 0; nt < 8; nt++){
            int col = nt * 16 + nn;
            float bval = bias[col];
            #pragma unroll
            for (int mt = 0; mt < 2; mt++){
                #pragma unroll
                for (int r = 0; r < 4; r++){
                    int row = row0 + mt * 16 + q * 4 + r;
                    if (row < M) Y[(size_t)row * HC + col] = (acc[mt][nt][r] + bval) * scale;
                }
            }
        }
    }
}

// ===================== fused per-node attention =====================
// quarter-wave = 1 node (16 nodes/block). lane-in-quarter li = h*4+j owns
// channels h*32+j*8..+7 and attr/QW dims j*8..+7. alpha reduce = 2 shfl levels.
// 2-edge batches, grouped online-softmax rescale. norm_a fused.
__device__ __forceinline__ float dot16(const uint4 kk, const uint4 aa,
                                       const float4 qA, const float4 qB,
                                       const float4 wA, const float4 wB){
    float p =           bflo(kk.x) * qA.x;
    p = fmaf(bfhi(kk.x), qA.y, p);
    p = fmaf(bflo(kk.y), qA.z, p);
    p = fmaf(bfhi(kk.y), qA.w, p);
    p = fmaf(bflo(kk.z), qB.x, p);
    p = fmaf(bfhi(kk.z), qB.y, p);
    p = fmaf(bflo(kk.w), qB.z, p);
    p = fmaf(bfhi(kk.w), qB.w, p);
    p = fmaf(bflo(aa.x), wA.x, p);
    p = fmaf(bfhi(aa.x), wA.y, p);
    p = fmaf(bflo(aa.y), wA.z, p);
    p = fmaf(bfhi(aa.y), wA.w, p);
    p = fmaf(bflo(aa.z), wB.x, p);
    p = fmaf(bfhi(aa.z), wB.y, p);
    p = fmaf(bflo(aa.w), wB.z, p);
    p = fmaf(bfhi(aa.w), wB.w, p);
    return p;
}

__device__ __forceinline__ uint4 packrow(const float* p){
    float4 x = *(const float4*)p;
    float4 y = *(const float4*)(p + 4);
    uint4 r;
    r.x = (unsigned)f2bf(x.x) | ((unsigned)f2bf(x.y) << 16);
    r.y = (unsigned)f2bf(x.z) | ((unsigned)f2bf(x.w) << 16);
    r.z = (unsigned)f2bf(y.x) | ((unsigned)f2bf(y.y) << 16);
    r.w = (unsigned)f2bf(y.z) | ((unsigned)f2bf(y.w) << 16);
    return r;
}

__global__ __launch_bounds__(256) void fused_attn_kernel(
    const float* __restrict__ qs, const float* __restrict__ qw,
    const ushort_t* __restrict__ kb, const ushort_t* __restrict__ vb,
    const float* __restrict__ skip, const float* __restrict__ We,
    const float* __restrict__ attr, const ushort_t* __restrict__ attr_bf, int perm_mode,
    const int* __restrict__ rowptr, const int2* __restrict__ es,
    const int* __restrict__ norder,
    float* __restrict__ acsr, float* __restrict__ a_out,
    const float* __restrict__ g, const float* __restrict__ be,
    float* __restrict__ out_f32, ushort_t* __restrict__ out_bf, int apply_ln)
{
    __shared__ float WeT[5120];         // 128 rows x stride 40 (bijective quad-rotated)
    __shared__ float SL[2304];          // 16 nodes x 144 (= 4 heads x 36) -- no overlap
    const int t = threadIdx.x;
    for (int idx = t; idx < ED * HC; idx += 256){
        int d = idx >> 7, c = idx & 127;
        WeT[weidx(c, d)] = We[idx];
    }
    __syncthreads();

    const int lane = t & 63, wvi = t >> 6;
    const int qq = lane >> 4, li = lane & 15;
    const int h = li >> 2, j = li & 3;
    const int gq = blockIdx.x * 16 + wvi * 4 + qq;
    if (gq >= N_NODES) return;
    const int n = norder[gq];
    const int ch = h * 32 + j * 8;
    const size_t nrow = (size_t)n * HC + ch;

    const float4 qA = *(const float4*)&qs[nrow];
    const float4 qB = *(const float4*)&qs[nrow + 4];
    const float4 wA = *(const float4*)&qw[nrow];
    const float4 wB = *(const float4*)&qw[nrow + 4];

    const int beg = rowptr[n], end = rowptr[n + 1];
    float m = -1e30f, s = 0.f;
    float acc[8] = {0,0,0,0,0,0,0,0};
    float S[8]   = {0,0,0,0,0,0,0,0};

    for (int i = beg; i < end; i += 2){
        const bool two = (i + 1 < end);
        const int2 e0 = es[i];
        const int2 e1 = two ? es[i + 1] : e0;
        const uint4 k0 = *(const uint4*)&kb[(size_t)e0.y * HC + ch];
        const uint4 k1 = *(const uint4*)&kb[(size_t)e1.y * HC + ch];
        const uint4 v0 = *(const uint4*)&vb[(size_t)e0.y * HC + ch];
        const uint4 v1 = *(const uint4*)&vb[(size_t)e1.y * HC + ch];
        uint4 a0u, a1u;
        if (perm_mode){
            a0u = *(const uint4*)&attr_bf[(size_t)i * ED + j * 8];
            a1u = two ? *(const uint4*)&attr_bf[(size_t)(i + 1) * ED + j * 8] : a0u;
        } else {
            a0u = packrow(&attr[(size_t)e0.x * ED + j * 8]);
            a1u = two ? packrow(&attr[(size_t)e1.x * ED + j * 8]) : a0u;
        }
        float p0 = dot16(k0, a0u, qA, qB, wA, wB);
        float p1 = dot16(k1, a1u, qA, qB, wA, wB);
        p0 += __shfl_xor(p0, 1);  p1 += __shfl_xor(p1, 1);
        p0 += __shfl_xor(p0, 2);  p1 += __shfl_xor(p1, 2);
        const float al0 = p0;
        const float al1 = two ? p1 : -1e38f;
        if (j == 0){
            acsr[(size_t)i * 4 + h] = al0;
            if (two) acsr[(size_t)(i + 1) * 4 + h] = al1;
        }
        const float mn = fmaxf(m, fmaxf(al0, al1));
        const float sc = __expf(m - mn);
        const float w0 = __expf(al0 - mn);
        const float w1 = __expf(al1 - mn);
        m = mn;
        s = fmaf(s, sc, w0 + w1);
        acc[0] = fmaf(acc[0], sc, fmaf(w0, bflo(v0.x), w1 * bflo(v1.x)));
        acc[1] = fmaf(acc[1], sc, fmaf(w0, bfhi(v0.x), w1 * bfhi(v1.x)));
        acc[2] = fmaf(acc[2], sc, fmaf(w0, bflo(v0.y), w1 * bflo(v1.y)));
        acc[3] = fmaf(acc[3], sc, fmaf(w0, bfhi(v0.y), w1 * bfhi(v1.y)));
        acc[4] = fmaf(acc[4], sc, fmaf(w0, bflo(v0.z), w1 * bflo(v1.z)));
        acc[5] = fmaf(acc[5], sc, fmaf(w0, bfhi(v0.z), w1 * bfhi(v1.z)));
        acc[6] = fmaf(acc[6], sc, fmaf(w0, bflo(v0.w), w1 * bflo(v1.w)));
        acc[7] = fmaf(acc[7], sc, fmaf(w0, bfhi(v0.w), w1 * bfhi(v1.w)));
        S[0] = fmaf(S[0], sc, fmaf(w0, bflo(a0u.x), w1 * bflo(a1u.x)));
        S[1] = fmaf(S[1], sc, fmaf(w0, bfhi(a0u.x), w1 * bfhi(a1u.x)));
        S[2] = fmaf(S[2], sc, fmaf(w0, bflo(a0u.y), w1 * bflo(a1u.y)));
        S[3] = fmaf(S[3], sc, fmaf(w0, bfhi(a0u.y), w1 * bfhi(a1u.y)));
        S[4] = fmaf(S[4], sc, fmaf(w0, bflo(a0u.z), w1 * bflo(a1u.z)));
        S[5] = fmaf(S[5], sc, fmaf(w0, bfhi(a0u.z), w1 * bfhi(a1u.z)));
        S[6] = fmaf(S[6], sc, fmaf(w0, bflo(a0u.w), w1 * bflo(a1u.w)));
        S[7] = fmaf(S[7], sc, fmaf(w0, bfhi(a0u.w), w1 * bfhi(a1u.w)));
    }

    // ---- E = We_h^T S_h via per-node LDS transpose ----
    const int nl = wvi * 4 + qq;
    const int sbase = nl * 144;         // 144 = 4 heads x 36 floats, no cross-node overlap
    const int hsk = h * 36;
    *(float4*)&SL[sbase + hsk + j * 8]     = make_float4(S[0], S[1], S[2], S[3]);
    *(float4*)&SL[sbase + hsk + j * 8 + 4] = make_float4(S[4], S[5], S[6], S[7]);
    asm volatile("" ::: "memory");     // in-wave LDS write->read ordering
    float E[8] = {0,0,0,0,0,0,0,0};
    #pragma unroll
    for (int d4 = 0; d4 < 8; d4++){
        const float4 sv = *(const float4*)&SL[sbase + hsk + d4 * 4];
        #pragma unroll
        for (int r = 0; r < 8; r++){
            const float4 wv = *(const float4*)&WeT[weidx(ch + r, d4 * 4)];
            E[r] = fmaf(sv.x, wv.x, fmaf(sv.y, wv.y, fmaf(sv.z, wv.z, fmaf(sv.w, wv.w, E[r]))));
        }
    }

    const float inv = 1.f / (s + 1e-16f);
    const float4 skA = *(const float4*)&skip[nrow];
    const float4 skB = *(const float4*)&skip[nrow + 4];
    float o[8];
    o[0] = (acc[0] + E[0]) * inv + skA.x;
    o[1] = (acc[1] + E[1]) * inv + skA.y;
    o[2] = (acc[2] + E[2]) * inv + skA.z;
    o[3] = (acc[3] + E[3]) * inv + skA.w;
    o[4] = (acc[4] + E[4]) * inv + skB.x;
    o[5] = (acc[5] + E[5]) * inv + skB.y;
    o[6] = (acc[6] + E[6]) * inv + skB.z;
    o[7] = (acc[7] + E[7]) * inv + skB.w;

    if (apply_ln){
        float s1 = 0.f, s2 = 0.f;
        #pragma unroll
        for (int r = 0; r < 8; r++){ s1 += o[r]; s2 = fmaf(o[r], o[r], s2); }
        #pragma unroll
        for (int off = 1; off <= 8; off <<= 1){
            s1 += __shfl_xor(s1, off);
            s2 += __shfl_xor(s2, off);
        }
        const float mu  = s1 * (1.f / 128.f);
        const float var = s2 * (1.f / 128.f) - mu * mu;
        const float ivs = rsqrtf(var + 1e-5f);
        const float4 gA = *(const float4*)&g[ch];
        const float4 gB = *(const float4*)&g[ch + 4];
        const float4 bA = *(const float4*)&be[ch];
        const float4 bB = *(const float4*)&be[ch + 4];
        o[0] = fmaxf((o[0] - mu) * ivs * gA.x + bA.x, 0.f);
        o[1] = fmaxf((o[1] - mu) * ivs * gA.y + bA.y, 0.f);
        o[2] = fmaxf((o[2] - mu) * ivs * gA.z + bA.z, 0.f);
        o[3] = fmaxf((o[3] - mu) * ivs * gA.w + bA.w, 0.f);
        o[4] = fmaxf((o[4] - mu) * ivs * gB.x + bB.x, 0.f);
        o[5] = fmaxf((o[5] - mu) * ivs * gB.y + bB.y, 0.f);
        o[6] = fmaxf((o[6] - mu) * ivs * gB.z + bB.z, 0.f);
        o[7] = fmaxf((o[7] - mu) * ivs * gB.w + bB.w, 0.f);
        uint4 st;
        st.x = (unsigned)f2bf(o[0]) | ((unsigned)f2bf(o[1]) << 16);
        st.y = (unsigned)f2bf(o[2]) | ((unsigned)f2bf(o[3]) << 16);
        st.z = (unsigned)f2bf(o[4]) | ((unsigned)f2bf(o[5]) << 16);
        st.w = (unsigned)f2bf(o[6]) | ((unsigned)f2bf(o[7]) << 16);
        *(uint4*)&out_bf[nrow] = st;
    } else {
        *(float4*)&out_f32[nrow]     = make_float4(o[0], o[1], o[2], o[3]);
        *(float4*)&out_f32[nrow + 4] = make_float4(o[4], o[5], o[6], o[7]);
    }

    // ---- fused norm_a ----
    const float mh = __shfl(m, (qq << 4) + ((li & 3) << 2));
    const float dh = __shfl(s, (qq << 4) + ((li & 3) << 2));
    const float ih = 1.f / (dh + 1e-16f);
    asm volatile("s_waitcnt vmcnt(0)" ::: "memory");   // our acsr stores visible
    for (int f = beg * 4 + li; f < end * 4; f += 16){
        const int e = es[f >> 2].x;
        a_out[(size_t)e * 4 + (li & 3)] = __expf(acsr[f] - mh) * ih;
    }
}

// ============================ launch ============================

extern "C" void kernel_launch(void* const* d_in, const int* in_sizes, int n_in,
                              void* d_out, int out_size, void* d_ws, size_t ws_size,
                              hipStream_t stream) {
    const float* x    = (const float*)d_in[0];
    const int*   ei   = (const int*)  d_in[1];
    const float* attr = (const float*)d_in[2];
    const float* gln[2]  = { (const float*)d_in[30], (const float*)d_in[32] };
    const float* beln[2] = { (const float*)d_in[31], (const float*)d_in[33] };

    float* out   = (float*)d_out;
    float* h_out = out;
    float* a_out[3] = { out + (size_t)N_NODES * HC,
                        out + (size_t)N_NODES * HC + (size_t)E_EDGES * 4,
                        out + (size_t)N_NODES * HC + (size_t)2 * E_EDGES * 4 };

    // ---- workspace layout (64B-aligned chunks); attr_bf LAST (perm-gated) ----
    char* base = (char*)d_ws;
    size_t off = 0;
    auto alloc = [&](size_t bytes) -> void* {
        void* p = base + off;
        off = (off + bytes + 63) & ~(size_t)63;
        return p;
    };
    const size_t NB = (size_t)N_NODES * HC;
    float* qbuf     = (float*)alloc(NB * 4);
    float* qwbuf    = (float*)alloc(NB * 4);
    ushort_t* kbf   = (ushort_t*)alloc(NB * 2);
    ushort_t* vbf   = (ushort_t*)alloc(NB * 2);
    float* sbuf     = (float*)alloc(NB * 4);
    int* rowptr     = (int*)alloc((N_NODES + 1) * 4);
    int* cnt        = (int*)alloc(N_NODES * 4);
    int* cursor     = (int*)alloc(N_NODES * 4);
    int* norder     = (int*)alloc(N_NODES * 4);
    int* bcnt       = (int*)alloc(64 * 4);
    int* bcur       = (int*)alloc(64 * 4);
    int2* es        = (int2*)alloc((size_t)E_EDGES * 8);
    ushort_t* Xbf   = (ushort_t*)alloc((size_t)N_NODES * 256 * 2);
    ushort_t* Hbf   = (ushort_t*)alloc(NB * 2);
    ushort_t* Bpack = (ushort_t*)alloc((size_t)256 * 640 * 2);
    float* acsr     = (float*)alloc((size_t)E_EDGES * 4 * 4);
    float* Wqe      = (float*)alloc((size_t)256 * HC * 4);
    float* qwb      = (float*)alloc(HC * 4);
    ushort_t* attr_bf = (ushort_t*)alloc((size_t)E_EDGES * ED * 2);
    const int perm_mode = (ws_size >= off) ? 1 : 0;

    const int* srcp = ei;
    const int* dstp = ei + E_EDGES;

    // ---- CSR build + degree sort + conversions (once per launch) ----
    zero_int_kernel<<<(N_NODES + 255) / 256, 256, 0, stream>>>(cnt, N_NODES);
    zero_int_kernel<<<1, 64, 0, stream>>>(bcnt, 64);
    hist_kernel<<<(E_EDGES + 255) / 256, 256, 0, stream>>>(dstp, cnt, E_EDGES);
    scan_kernel<<<1, 1024, 0, stream>>>(cnt, rowptr, cursor);
    scatter_kernel<<<(E_EDGES + 255) / 256, 256, 0, stream>>>(srcp, dstp, cursor, es, E_EDGES);
    dhist_kernel<<<(N_NODES + 255) / 256, 256, 0, stream>>>(rowptr, bcnt);
    dscan_kernel<<<1, 64, 0, stream>>>(bcnt, bcur);
    dscatter_kernel<<<(N_NODES + 255) / 256, 256, 0, stream>>>(rowptr, bcur, norder);
    if (perm_mode)
        permute_attr_kernel<<<(E_EDGES * 16 + 255) / 256, 256, 0, stream>>>(attr, es, attr_bf, E_EDGES);
    convert_bf16_kernel<<<((N_NODES * 256 / 4) + 255) / 256, 256, 0, stream>>>(x, Xbf, N_NODES * 256 / 4);

    const int gemm_grid = (N_NODES + 31) / 32;
    const int attn_grid = (N_NODES + 15) / 16;

    for (int l = 0; l < 3; l++){
        const float* Wq = (const float*)d_in[3 + 9 * l + 0];
        const float* bq = (const float*)d_in[3 + 9 * l + 1];
        const float* Wk = (const float*)d_in[3 + 9 * l + 2];
        const float* bk = (const float*)d_in[3 + 9 * l + 3];
        const float* Wv = (const float*)d_in[3 + 9 * l + 4];
        const float* bv = (const float*)d_in[3 + 9 * l + 5];
        const float* We = (const float*)d_in[3 + 9 * l + 6];
        const float* Ws = (const float*)d_in[3 + 9 * l + 7];
        const float* bs = (const float*)d_in[3 + 9 * l + 8];
        const int K = (l == 0) ? 256 : 128;

        wqe_kernel<<<(K * HC + 255) / 256, 256, 0, stream>>>(Wq, bq, We, Wqe, qwb, K);
        pack_w_kernel<<<(K * 640 + 255) / 256, 256, 0, stream>>>(Wq, Wk, Wv, Ws, Wqe, Bpack, K);
        if (l == 0)
            gemm_mfma<256><<<gemm_grid, 320, 0, stream>>>(Xbf, Bpack, bq, bk, bv, bs, qwb,
                                                          qbuf, kbf, vbf, sbuf, qwbuf, N_NODES);
        else
            gemm_mfma<128><<<gemm_grid, 320, 0, stream>>>(Hbf, Bpack, bq, bk, bv, bs, qwb,
                                                          qbuf, kbf, vbf, sbuf, qwbuf, N_NODES);

        const float* gg = (l < 2) ? gln[l] : nullptr;
        const float* bb = (l < 2) ? beln[l] : nullptr;
        fused_attn_kernel<<<attn_grid, 256, 0, stream>>>(
            qbuf, qwbuf, kbf, vbf, sbuf, We, attr, attr_bf, perm_mode,
            rowptr, es, norder, acsr, a_out[l], gg, bb,
            (l < 2) ? nullptr : h_out, (l < 2) ? Hbf : nullptr, (l < 2) ? 1 : 0);
    }
}

// Round 5
// 1109.459 us; speedup vs baseline: 1.2901x; 1.1547x over previous
//
#include <hip/hip_runtime.h>
#include <math.h>

#define N_NODES 50000
#define E_EDGES 800000
#define HC 128
#define ED 32

typedef __attribute__((ext_vector_type(8))) short bf16x8;
typedef __attribute__((ext_vector_type(4))) float f32x4;
typedef unsigned short ushort_t;

__device__ __forceinline__ ushort_t f2bf(float f){
    unsigned u = __float_as_uint(f);
    return (ushort_t)((u + 0x7FFFu + ((u >> 16) & 1u)) >> 16);   // RNE
}
__device__ __forceinline__ float bflo(unsigned u){ return __uint_as_float(u << 16); }
__device__ __forceinline__ float bfhi(unsigned u){ return __uint_as_float(u & 0xffff0000u); }

// ============================ CSR build ============================

__global__ void hist_kernel(const int* __restrict__ dst, int* __restrict__ cnt, int n_edges){
    int e = blockIdx.x * blockDim.x + threadIdx.x;
    if (e < n_edges) atomicAdd(&cnt[dst[e]], 1);
}

// single block: prefix-sum (rowptr/cursor) + degree-bucket sort (norder) in one launch
__global__ __launch_bounds__(1024) void scan_sort_kernel(
    const int* __restrict__ cnt, int* __restrict__ rowptr,
    int* __restrict__ cursor, int* __restrict__ norder)
{
    __shared__ int part[1024];
    __shared__ int bins[64];
    __shared__ int binoff[64];
    const int t = threadIdx.x;
    const int CH = (N_NODES + 1023) / 1024;
    const int base = t * CH;
    int s = 0;
    for (int i = 0; i < CH; i++){
        int idx = base + i;
        if (idx < N_NODES) s += cnt[idx];
    }
    part[t] = s;
    __syncthreads();
    for (int off = 1; off < 1024; off <<= 1){
        int v = (t >= off) ? part[t - off] : 0;
        __syncthreads();
        part[t] += v;
        __syncthreads();
    }
    int off = (t == 0) ? 0 : part[t - 1];
    for (int i = 0; i < CH; i++){
        int idx = base + i;
        if (idx < N_NODES){
            int c = cnt[idx];
            rowptr[idx] = off;
            cursor[idx] = off;
            off += c;
        }
    }
    if (t == 1023) rowptr[N_NODES] = part[1023];

    // ---- degree-bucket sort: norder groups equal-degree nodes ----
    if (t < 64) bins[t] = 0;
    __syncthreads();
    for (int i = t; i < N_NODES; i += 1024){
        int d = cnt[i];
        if (d > 63) d = 63;
        atomicAdd(&bins[d], 1);
    }
    __syncthreads();
    if (t == 0){
        int acc = 0;
        for (int d = 0; d < 64; d++){ int c = bins[d]; binoff[d] = acc; acc += c; }
    }
    __syncthreads();
    if (t < 64) bins[t] = binoff[t];
    __syncthreads();
    for (int i = t; i < N_NODES; i += 1024){
        int d = cnt[i];
        if (d > 63) d = 63;
        int pos = atomicAdd(&bins[d], 1);
        norder[pos] = i;
    }
}

__global__ void scatter_kernel(const int* __restrict__ src, const int* __restrict__ dst,
                               int* __restrict__ cursor, int2* __restrict__ es, int n_edges){
    int e = blockIdx.x * blockDim.x + threadIdx.x;
    if (e < n_edges){
        int d = dst[e];
        int pos = atomicAdd(&cursor[d], 1);
        es[pos] = make_int2(e, src[e]);
    }
}

// ============== fused tail: permute_attr + x->bf16 + pack 3 layers (+Wqe fold, qwb) ==============
// pack: Bpack[((k>>3)*640 + n)*8 + (k&7)] = W_{n>>7}[k*128 + (n&127)], n>=512 -> Wqe fold
__device__ __forceinline__ void pack_item(const float* __restrict__ Wq, const float* __restrict__ Wk,
                                          const float* __restrict__ Wv, const float* __restrict__ Ws,
                                          const float* __restrict__ We, ushort_t* __restrict__ Bp,
                                          int K, int item){
    int n = item % 640, k = item / 640;
    float val;
    if (n < 512){
        const float* W = (n < 128) ? Wq : (n < 256) ? Wk : (n < 384) ? Wv : Ws;
        val = W[k * HC + (n & 127)];
    } else {
        int col = n - 512, h5 = (col >> 5) * 32, d = col & 31;
        float acc = 0.f;
        for (int c = 0; c < 32; c++)
            acc = fmaf(Wq[k * HC + h5 + c], We[d * HC + h5 + c], acc);
        val = acc;
    }
    Bp[(((size_t)(k >> 3)) * 640 + n) * 8 + (k & 7)] = f2bf(val);
}

#define T_S0 12800000            // permute_attr items (E*16)
#define T_S1 16000000            // + convert items (N*256/4)
#define T_S2 16163840            // + pack L0 (256*640)
#define T_S3 16245760            // + pack L1 (128*640)
#define T_S4 16327680            // + pack L2 (128*640)
#define T_S5 16328064            // + qwb (3*128)

__global__ __launch_bounds__(256) void tail_kernel(
    const float* __restrict__ attr, const int2* __restrict__ es,
    const float* __restrict__ x, int perm_mode,
    ushort_t* __restrict__ attr_bf, ushort_t* __restrict__ Xbf,
    const float* __restrict__ Wq0, const float* __restrict__ bq0, const float* __restrict__ Wk0,
    const float* __restrict__ Wv0, const float* __restrict__ Ws0, const float* __restrict__ We0,
    const float* __restrict__ Wq1, const float* __restrict__ bq1, const float* __restrict__ Wk1,
    const float* __restrict__ Wv1, const float* __restrict__ Ws1, const float* __restrict__ We1,
    const float* __restrict__ Wq2, const float* __restrict__ bq2, const float* __restrict__ Wk2,
    const float* __restrict__ Wv2, const float* __restrict__ Ws2, const float* __restrict__ We2,
    ushort_t* __restrict__ Bp0, ushort_t* __restrict__ Bp1, ushort_t* __restrict__ Bp2,
    float* __restrict__ qwb3)
{
    const int stride = gridDim.x * blockDim.x;
    for (int gi = blockIdx.x * blockDim.x + threadIdx.x; gi < T_S5; gi += stride){
        if (gi < T_S0){
            if (perm_mode){
                int grp = gi >> 4, lane = gi & 15;
                int e = es[grp].x;
                const float2 v = *(const float2*)&attr[(size_t)e * ED + lane * 2];
                unsigned r = (unsigned)f2bf(v.x) | ((unsigned)f2bf(v.y) << 16);
                ((unsigned*)attr_bf)[(size_t)grp * (ED / 2) + lane] = r;
            }
        } else if (gi < T_S1){
            int i = gi - T_S0;
            float4 v = ((const float4*)x)[i];
            ushort_t r0 = f2bf(v.x), r1 = f2bf(v.y), r2 = f2bf(v.z), r3 = f2bf(v.w);
            ((ushort4*)Xbf)[i] = make_ushort4(r0, r1, r2, r3);
        } else if (gi < T_S2){
            pack_item(Wq0, Wk0, Wv0, Ws0, We0, Bp0, 256, gi - T_S1);
        } else if (gi < T_S3){
            pack_item(Wq1, Wk1, Wv1, Ws1, We1, Bp1, 128, gi - T_S2);
        } else if (gi < T_S4){
            pack_item(Wq2, Wk2, Wv2, Ws2, We2, Bp2, 128, gi - T_S3);
        } else {
            int f = gi - T_S4;
            int l = f >> 7, t2 = f & 127;
            const float* bq = (l == 0) ? bq0 : (l == 1) ? bq1 : bq2;
            const float* We = (l == 0) ? We0 : (l == 1) ? We1 : We2;
            int h5 = (t2 >> 5) * 32, d = t2 & 31;
            float acc = 0.f;
            for (int c = 0; c < 32; c++)
                acc = fmaf(bq[h5 + c], We[d * HC + h5 + c], acc);
            qwb3[l * HC + t2] = acc;
        }
    }
}

// ===================== MFMA GEMM: [M,K]bf16 @ [K,640]bf16 + bias ====
// 5 waves; w: 0=q(f32,*scale) 1=k(bf16) 2=v(bf16) 3=skip(f32) 4=QW(f32,*scale)
template<int K>
__global__ __launch_bounds__(320) void gemm_mfma(
    const ushort_t* __restrict__ Xbf, const ushort_t* __restrict__ Bpack,
    const float* __restrict__ b0, const float* __restrict__ b1,
    const float* __restrict__ b2, const float* __restrict__ b3,
    const float* __restrict__ b4,
    float* __restrict__ Yq, ushort_t* __restrict__ Ykbf,
    ushort_t* __restrict__ Yvbf, float* __restrict__ Ys,
    float* __restrict__ Yw, int M)
{
    const int w = threadIdx.x >> 6;
    const int lane = threadIdx.x & 63;
    const int q = lane >> 4, nn = lane & 15;
    const int row0 = blockIdx.x * 32;

    f32x4 acc[2][8];
    #pragma unroll
    for (int mt = 0; mt < 2; mt++)
        #pragma unroll
        for (int nt = 0; nt < 8; nt++)
            acc[mt][nt] = (f32x4){0.f, 0.f, 0.f, 0.f};

    const int r0 = row0 + nn;
    const int r1 = row0 + 16 + nn;
    const bf16x8 zf = (bf16x8){0,0,0,0,0,0,0,0};

    #pragma unroll
    for (int kc = 0; kc < K / 32; kc++){
        bf16x8 a0 = (r0 < M) ? *(const bf16x8*)&Xbf[(size_t)r0 * K + kc * 32 + q * 8] : zf;
        bf16x8 a1 = (r1 < M) ? *(const bf16x8*)&Xbf[(size_t)r1 * K + kc * 32 + q * 8] : zf;
        bf16x8 b[8];
        #pragma unroll
        for (int nt = 0; nt < 8; nt++){
            int n = w * 128 + nt * 16 + nn;
            b[nt] = *(const bf16x8*)&Bpack[(((size_t)(kc * 4 + q)) * 640 + n) * 8];
        }
        #pragma unroll
        for (int nt = 0; nt < 8; nt++){
            acc[0][nt] = __builtin_amdgcn_mfma_f32_16x16x32_bf16(a0, b[nt], acc[0][nt], 0, 0, 0);
            acc[1][nt] = __builtin_amdgcn_mfma_f32_16x16x32_bf16(a1, b[nt], acc[1][nt], 0, 0, 0);
        }
    }

    const float scale = (w == 0 || w == 4) ? 0.17677669529663687f : 1.f;
    const float* bias = (w == 0) ? b0 : (w == 1) ? b1 : (w == 2) ? b2 : (w == 3) ? b3 : b4;

    if (w == 1 || w == 2){
        ushort_t* Yb = (w == 1) ? Ykbf : Yvbf;
        #pragma unroll
        for (int nt = 0; nt < 8; nt++){
            int col = nt * 16 + nn;
            float bval = bias[col];
            #pragma unroll
            for (int mt = 0; mt < 2; mt++){
                #pragma unroll
                for (int r = 0; r < 4; r++){
                    int row = row0 + mt * 16 + q * 4 + r;
                    if (row < M) Yb[(size_t)row * HC + col] = f2bf(acc[mt][nt][r] + bval);
                }
            }
        }
    } else {
        float* Y = (w == 0) ? Yq : (w == 3) ? Ys : Yw;
        #pragma unroll
        for (int nt = 0; nt < 8; nt++){
            int col = nt * 16 + nn;
            float bval = bias[col];
            #pragma unroll
            for (int mt = 0; mt < 2; mt++){
                #pragma unroll
                for (int r = 0; r < 4; r++){
                    int row = row0 + mt * 16 + q * 4 + r;
                    if (row < M) Y[(size_t)row * HC + col] = (acc[mt][nt][r] + bval) * scale;
                }
            }
        }
    }
}

// ===================== fused per-node attention =====================
// quarter-wave = 1 node (16 nodes/block). lane-in-quarter li = h*4+j owns
// channels h*32+j*8..+7 and attr/QW dims j*8..+7. alpha reduce = 2 shfl levels.
// WeT in LDS as packed bf16 (10.2 KB, pair-rotated conflict-free) -> 19.5 KB total
// -> 8 blocks/CU occupancy. norm_a fused.
__device__ __forceinline__ float dot16(const uint4 kk, const uint4 aa,
                                       const float4 qA, const float4 qB,
                                       const float4 wA, const float4 wB){
    float p =           bflo(kk.x) * qA.x;
    p = fmaf(bfhi(kk.x), qA.y, p);
    p = fmaf(bflo(kk.y), qA.z, p);
    p = fmaf(bfhi(kk.y), qA.w, p);
    p = fmaf(bflo(kk.z), qB.x, p);
    p = fmaf(bfhi(kk.z), qB.y, p);
    p = fmaf(bflo(kk.w), qB.z, p);
    p = fmaf(bfhi(kk.w), qB.w, p);
    p = fmaf(bflo(aa.x), wA.x, p);
    p = fmaf(bfhi(aa.x), wA.y, p);
    p = fmaf(bflo(aa.y), wA.z, p);
    p = fmaf(bfhi(aa.y), wA.w, p);
    p = fmaf(bflo(aa.z), wB.x, p);
    p = fmaf(bfhi(aa.z), wB.y, p);
    p = fmaf(bflo(aa.w), wB.z, p);
    p = fmaf(bfhi(aa.w), wB.w, p);
    return p;
}

__device__ __forceinline__ uint4 packrow(const float* p){
    float4 x = *(const float4*)p;
    float4 y = *(const float4*)(p + 4);
    uint4 r;
    r.x = (unsigned)f2bf(x.x) | ((unsigned)f2bf(x.y) << 16);
    r.y = (unsigned)f2bf(x.z) | ((unsigned)f2bf(x.w) << 16);
    r.z = (unsigned)f2bf(y.x) | ((unsigned)f2bf(y.y) << 16);
    r.w = (unsigned)f2bf(y.z) | ((unsigned)f2bf(y.w) << 16);
    return r;
}

__global__ __launch_bounds__(256) void fused_attn_kernel(
    const float* __restrict__ qs, const float* __restrict__ qw,
    const ushort_t* __restrict__ kb, const ushort_t* __restrict__ vb,
    const float* __restrict__ skip, const float* __restrict__ We,
    const float* __restrict__ attr, const ushort_t* __restrict__ attr_bf, int perm_mode,
    const int* __restrict__ rowptr, const int2* __restrict__ es,
    const int* __restrict__ norder,
    float* __restrict__ acsr, float* __restrict__ a_out,
    const float* __restrict__ g, const float* __restrict__ be,
    float* __restrict__ out_f32, ushort_t* __restrict__ out_bf, int apply_ln)
{
    // WeTb[c][pair p of d] packed bf16: u32 word w=d>>1 stored at
    // c*20 + (((w>>1)+(c>>3))&7)*2 + (w&1). Bijective per row; read bank-unit
    // = (d4+li)&7 -> 2 lanes/unit, same addr -> broadcast (conflict-free).
    __shared__ unsigned WeTb[2560];     // 128 x 20 u32 = 10.2 KB
    __shared__ float SL[2304];          // 16 nodes x 144 (= 4 heads x 36)
    const int t = threadIdx.x;
    for (int idx = t; idx < 2048; idx += 256){
        int w = idx & 15;               // word index (d = 2w, 2w+1)
        int c = idx >> 4;               // channel
        float lo = We[(2 * w) * HC + c];
        float hi = We[(2 * w + 1) * HC + c];
        unsigned u = (unsigned)f2bf(lo) | ((unsigned)f2bf(hi) << 16);
        WeTb[c * 20 + ((((w >> 1) + (c >> 3)) & 7) << 1) + (w & 1)] = u;
    }
    __syncthreads();

    const int lane = t & 63, wvi = t >> 6;
    const int qq = lane >> 4, li = lane & 15;
    const int h = li >> 2, j = li & 3;
    const int gq = blockIdx.x * 16 + wvi * 4 + qq;
    if (gq >= N_NODES) return;
    const int n = norder[gq];
    const int ch = h * 32 + j * 8;
    const size_t nrow = (size_t)n * HC + ch;

    const float4 qA = *(const float4*)&qs[nrow];
    const float4 qB = *(const float4*)&qs[nrow + 4];
    const float4 wA = *(const float4*)&qw[nrow];
    const float4 wB = *(const float4*)&qw[nrow + 4];

    const int beg = rowptr[n], end = rowptr[n + 1];
    float m = -1e30f, s = 0.f;
    float acc[8] = {0,0,0,0,0,0,0,0};
    float S[8]   = {0,0,0,0,0,0,0,0};

    for (int i = beg; i < end; i += 2){
        const bool two = (i + 1 < end);
        const int2 e0 = es[i];
        const int2 e1 = two ? es[i + 1] : e0;
        const uint4 k0 = *(const uint4*)&kb[(size_t)e0.y * HC + ch];
        const uint4 k1 = *(const uint4*)&kb[(size_t)e1.y * HC + ch];
        const uint4 v0 = *(const uint4*)&vb[(size_t)e0.y * HC + ch];
        const uint4 v1 = *(const uint4*)&vb[(size_t)e1.y * HC + ch];
        uint4 a0u, a1u;
        if (perm_mode){
            a0u = *(const uint4*)&attr_bf[(size_t)i * ED + j * 8];
            a1u = two ? *(const uint4*)&attr_bf[(size_t)(i + 1) * ED + j * 8] : a0u;
        } else {
            a0u = packrow(&attr[(size_t)e0.x * ED + j * 8]);
            a1u = two ? packrow(&attr[(size_t)e1.x * ED + j * 8]) : a0u;
        }
        float p0 = dot16(k0, a0u, qA, qB, wA, wB);
        float p1 = dot16(k1, a1u, qA, qB, wA, wB);
        p0 += __shfl_xor(p0, 1);  p1 += __shfl_xor(p1, 1);
        p0 += __shfl_xor(p0, 2);  p1 += __shfl_xor(p1, 2);
        const float al0 = p0;
        const float al1 = two ? p1 : -1e38f;
        if (j == 0){
            acsr[(size_t)i * 4 + h] = al0;
            if (two) acsr[(size_t)(i + 1) * 4 + h] = al1;
        }
        const float mn = fmaxf(m, fmaxf(al0, al1));
        const float sc = __expf(m - mn);
        const float w0 = __expf(al0 - mn);
        const float w1 = __expf(al1 - mn);
        m = mn;
        s = fmaf(s, sc, w0 + w1);
        acc[0] = fmaf(acc[0], sc, fmaf(w0, bflo(v0.x), w1 * bflo(v1.x)));
        acc[1] = fmaf(acc[1], sc, fmaf(w0, bfhi(v0.x), w1 * bfhi(v1.x)));
        acc[2] = fmaf(acc[2], sc, fmaf(w0, bflo(v0.y), w1 * bflo(v1.y)));
        acc[3] = fmaf(acc[3], sc, fmaf(w0, bfhi(v0.y), w1 * bfhi(v1.y)));
        acc[4] = fmaf(acc[4], sc, fmaf(w0, bflo(v0.z), w1 * bflo(v1.z)));
        acc[5] = fmaf(acc[5], sc, fmaf(w0, bfhi(v0.z), w1 * bfhi(v1.z)));
        acc[6] = fmaf(acc[6], sc, fmaf(w0, bflo(v0.w), w1 * bflo(v1.w)));
        acc[7] = fmaf(acc[7], sc, fmaf(w0, bfhi(v0.w), w1 * bfhi(v1.w)));
        S[0] = fmaf(S[0], sc, fmaf(w0, bflo(a0u.x), w1 * bflo(a1u.x)));
        S[1] = fmaf(S[1], sc, fmaf(w0, bfhi(a0u.x), w1 * bfhi(a1u.x)));
        S[2] = fmaf(S[2], sc, fmaf(w0, bflo(a0u.y), w1 * bflo(a1u.y)));
        S[3] = fmaf(S[3], sc, fmaf(w0, bfhi(a0u.y), w1 * bfhi(a1u.y)));
        S[4] = fmaf(S[4], sc, fmaf(w0, bflo(a0u.z), w1 * bflo(a1u.z)));
        S[5] = fmaf(S[5], sc, fmaf(w0, bfhi(a0u.z), w1 * bfhi(a1u.z)));
        S[6] = fmaf(S[6], sc, fmaf(w0, bflo(a0u.w), w1 * bflo(a1u.w)));
        S[7] = fmaf(S[7], sc, fmaf(w0, bfhi(a0u.w), w1 * bfhi(a1u.w)));
    }

    // ---- E = We_h^T S_h via per-node LDS transpose ----
    const int nl = wvi * 4 + qq;
    const int sbase = nl * 144;
    const int hsk = h * 36;
    *(float4*)&SL[sbase + hsk + j * 8]     = make_float4(S[0], S[1], S[2], S[3]);
    *(float4*)&SL[sbase + hsk + j * 8 + 4] = make_float4(S[4], S[5], S[6], S[7]);
    asm volatile("" ::: "memory");     // in-wave LDS write->read ordering
    float E[8] = {0,0,0,0,0,0,0,0};
    #pragma unroll
    for (int d4 = 0; d4 < 8; d4++){
        const float4 sv = *(const float4*)&SL[sbase + hsk + d4 * 4];
        const int rot = ((d4 + li) & 7) << 1;
        #pragma unroll
        for (int r = 0; r < 8; r++){
            const uint2 wu = *(const uint2*)&WeTb[(ch + r) * 20 + rot];
            E[r] = fmaf(sv.x, bflo(wu.x), fmaf(sv.y, bfhi(wu.x),
                   fmaf(sv.z, bflo(wu.y), fmaf(sv.w, bfhi(wu.y), E[r]))));
        }
    }

    const float inv = 1.f / (s + 1e-16f);
    const float4 skA = *(const float4*)&skip[nrow];
    const float4 skB = *(const float4*)&skip[nrow + 4];
    float o[8];
    o[0] = (acc[0] + E[0]) * inv + skA.x;
    o[1] = (acc[1] + E[1]) * inv + skA.y;
    o[2] = (acc[2] + E[2]) * inv + skA.z;
    o[3] = (acc[3] + E[3]) * inv + skA.w;
    o[4] = (acc[4] + E[4]) * inv + skB.x;
    o[5] = (acc[5] + E[5]) * inv + skB.y;
    o[6] = (acc[6] + E[6]) * inv + skB.z;
    o[7] = (acc[7] + E[7]) * inv + skB.w;

    if (apply_ln){
        float s1 = 0.f, s2 = 0.f;
        #pragma unroll
        for (int r = 0; r < 8; r++){ s1 += o[r]; s2 = fmaf(o[r], o[r], s2); }
        #pragma unroll
        for (int off = 1; off <= 8; off <<= 1){
            s1 += __shfl_xor(s1, off);
            s2 += __shfl_xor(s2, off);
        }
        const float mu  = s1 * (1.f / 128.f);
        const float var = s2 * (1.f / 128.f) - mu * mu;
        const float ivs = rsqrtf(var + 1e-5f);
        const float4 gA = *(const float4*)&g[ch];
        const float4 gB = *(const float4*)&g[ch + 4];
        const float4 bA = *(const float4*)&be[ch];
        const float4 bB = *(const float4*)&be[ch + 4];
        o[0] = fmaxf((o[0] - mu) * ivs * gA.x + bA.x, 0.f);
        o[1] = fmaxf((o[1] - mu) * ivs * gA.y + bA.y, 0.f);
        o[2] = fmaxf((o[2] - mu) * ivs * gA.z + bA.z, 0.f);
        o[3] = fmaxf((o[3] - mu) * ivs * gA.w + bA.w, 0.f);
        o[4] = fmaxf((o[4] - mu) * ivs * gB.x + bB.x, 0.f);
        o[5] = fmaxf((o[5] - mu) * ivs * gB.y + bB.y, 0.f);
        o[6] = fmaxf((o[6] - mu) * ivs * gB.z + bB.z, 0.f);
        o[7] = fmaxf((o[7] - mu) * ivs * gB.w + bB.w, 0.f);
        uint4 st;
        st.x = (unsigned)f2bf(o[0]) | ((unsigned)f2bf(o[1]) << 16);
        st.y = (unsigned)f2bf(o[2]) | ((unsigned)f2bf(o[3]) << 16);
        st.z = (unsigned)f2bf(o[4]) | ((unsigned)f2bf(o[5]) << 16);
        st.w = (unsigned)f2bf(o[6]) | ((unsigned)f2bf(o[7]) << 16);
        *(uint4*)&out_bf[nrow] = st;
    } else {
        *(float4*)&out_f32[nrow]     = make_float4(o[0], o[1], o[2], o[3]);
        *(float4*)&out_f32[nrow + 4] = make_float4(o[4], o[5], o[6], o[7]);
    }

    // ---- fused norm_a ----
    const float mh = __shfl(m, (qq << 4) + ((li & 3) << 2));
    const float dh = __shfl(s, (qq << 4) + ((li & 3) << 2));
    const float ih = 1.f / (dh + 1e-16f);
    asm volatile("s_waitcnt vmcnt(0)" ::: "memory");   // our acsr stores visible
    for (int f = beg * 4 + li; f < end * 4; f += 16){
        const int e = es[f >> 2].x;
        a_out[(size_t)e * 4 + (li & 3)] = __expf(acsr[f] - mh) * ih;
    }
}

// ============================ launch ============================

extern "C" void kernel_launch(void* const* d_in, const int* in_sizes, int n_in,
                              void* d_out, int out_size, void* d_ws, size_t ws_size,
                              hipStream_t stream) {
    const float* x    = (const float*)d_in[0];
    const int*   ei   = (const int*)  d_in[1];
    const float* attr = (const float*)d_in[2];
    const float* gln[2]  = { (const float*)d_in[30], (const float*)d_in[32] };
    const float* beln[2] = { (const float*)d_in[31], (const float*)d_in[33] };

    float* out   = (float*)d_out;
    float* h_out = out;
    float* a_out[3] = { out + (size_t)N_NODES * HC,
                        out + (size_t)N_NODES * HC + (size_t)E_EDGES * 4,
                        out + (size_t)N_NODES * HC + (size_t)2 * E_EDGES * 4 };

    // ---- workspace layout (64B-aligned chunks); attr_bf LAST (perm-gated) ----
    char* base = (char*)d_ws;
    size_t off = 0;
    auto alloc = [&](size_t bytes) -> void* {
        void* p = base + off;
        off = (off + bytes + 63) & ~(size_t)63;
        return p;
    };
    const size_t NB = (size_t)N_NODES * HC;
    float* qbuf     = (float*)alloc(NB * 4);
    float* qwbuf    = (float*)alloc(NB * 4);
    ushort_t* kbf   = (ushort_t*)alloc(NB * 2);
    ushort_t* vbf   = (ushort_t*)alloc(NB * 2);
    float* sbuf     = (float*)alloc(NB * 4);
    int* rowptr     = (int*)alloc((N_NODES + 1) * 4);
    int* cnt        = (int*)alloc(N_NODES * 4);
    int* cursor     = (int*)alloc(N_NODES * 4);
    int* norder     = (int*)alloc(N_NODES * 4);
    int2* es        = (int2*)alloc((size_t)E_EDGES * 8);
    ushort_t* Xbf   = (ushort_t*)alloc((size_t)N_NODES * 256 * 2);
    ushort_t* Hbf   = (ushort_t*)alloc(NB * 2);
    ushort_t* Bp0   = (ushort_t*)alloc((size_t)256 * 640 * 2);
    ushort_t* Bp1   = (ushort_t*)alloc((size_t)128 * 640 * 2);
    ushort_t* Bp2   = (ushort_t*)alloc((size_t)128 * 640 * 2);
    float* acsr     = (float*)alloc((size_t)E_EDGES * 4 * 4);
    float* qwb3     = (float*)alloc((size_t)3 * HC * 4);
    ushort_t* attr_bf = (ushort_t*)alloc((size_t)E_EDGES * ED * 2);
    const int perm_mode = (ws_size >= off) ? 1 : 0;

    const int* srcp = ei;
    const int* dstp = ei + E_EDGES;

    // ---- prep: 1 memset + 4 kernels ----
    hipMemsetAsync(cnt, 0, (size_t)N_NODES * 4, stream);
    hist_kernel<<<(E_EDGES + 255) / 256, 256, 0, stream>>>(dstp, cnt, E_EDGES);
    scan_sort_kernel<<<1, 1024, 0, stream>>>(cnt, rowptr, cursor, norder);
    scatter_kernel<<<(E_EDGES + 255) / 256, 256, 0, stream>>>(srcp, dstp, cursor, es, E_EDGES);
    tail_kernel<<<4096, 256, 0, stream>>>(
        attr, es, x, perm_mode, attr_bf, Xbf,
        (const float*)d_in[3],  (const float*)d_in[4],  (const float*)d_in[5],
        (const float*)d_in[7],  (const float*)d_in[10], (const float*)d_in[9],
        (const float*)d_in[12], (const float*)d_in[13], (const float*)d_in[14],
        (const float*)d_in[16], (const float*)d_in[19], (const float*)d_in[18],
        (const float*)d_in[21], (const float*)d_in[22], (const float*)d_in[23],
        (const float*)d_in[25], (const float*)d_in[28], (const float*)d_in[27],
        Bp0, Bp1, Bp2, qwb3);

    const int gemm_grid = (N_NODES + 31) / 32;
    const int attn_grid = (N_NODES + 15) / 16;
    ushort_t* Bps[3] = { Bp0, Bp1, Bp2 };

    for (int l = 0; l < 3; l++){
        const float* bq = (const float*)d_in[3 + 9 * l + 1];
        const float* bk = (const float*)d_in[3 + 9 * l + 3];
        const float* bv = (const float*)d_in[3 + 9 * l + 5];
        const float* We = (const float*)d_in[3 + 9 * l + 6];
        const float* bs = (const float*)d_in[3 + 9 * l + 8];

        if (l == 0)
            gemm_mfma<256><<<gemm_grid, 320, 0, stream>>>(Xbf, Bps[l], bq, bk, bv, bs, qwb3 + 128 * l,
                                                          qbuf, kbf, vbf, sbuf, qwbuf, N_NODES);
        else
            gemm_mfma<128><<<gemm_grid, 320, 0, stream>>>(Hbf, Bps[l], bq, bk, bv, bs, qwb3 + 128 * l,
                                                          qbuf, kbf, vbf, sbuf, qwbuf, N_NODES);

        const float* gg = (l < 2) ? gln[l] : nullptr;
        const float* bb = (l < 2) ? beln[l] : nullptr;
        fused_attn_kernel<<<attn_grid, 256, 0, stream>>>(
            qbuf, qwbuf, kbf, vbf, sbuf, We, attr, attr_bf, perm_mode,
            rowptr, es, norder, acsr, a_out[l], gg, bb,
            (l < 2) ? nullptr : h_out, (l < 2) ? Hbf : nullptr, (l < 2) ? 1 : 0);
    }
}